// Round 9
// baseline (554.375 us; speedup 1.0000x reference)
//
#include <hip/hip_runtime.h>
#include <math.h>

#define T_LEN 4096
#define C_LEN 256
#define B_LEN 16
#define LOG2E 1.4426950408889634f

// ---------------------------------------------------------------------------
// Compile-time Gaussian kernel bank (matches numpy: exp(-0.5*(j/s)^2), trunc
// at r=int(4*s), normalized by sum+1e-12). Values become instruction literals.
// ---------------------------------------------------------------------------
constexpr double cexp(double x) {
    double y = x * (1.0 / 1024.0);
    double t = 1.0, term = 1.0;
    for (int i = 1; i <= 12; ++i) { term *= y / i; t += term; }
    for (int i = 0; i < 10; ++i) t = t * t;   // ^1024
    return t;
}

constexpr int RAD[5] = {10, 16, 24, 36, 56};

struct Bank { float g[5][57]; };

constexpr Bank make_bank() {
    Bank b{};
    const double sig[5] = {2.5, 4.0, 6.0, 9.0, 14.0};
    for (int k = 0; k < 5; ++k) {
        double w[57] = {};
        for (int j = 0; j <= RAD[k]; ++j)
            w[j] = cexp(-0.5 * (double)(j * j) / (sig[k] * sig[k]));
        double s = w[0];
        for (int j = 1; j <= RAD[k]; ++j) s += 2.0 * w[j];
        s += 1e-12;
        for (int j = 0; j <= RAD[k]; ++j) b.g[k][j] = (float)(w[j] / s);
    }
    return b;
}

constexpr Bank BANK = make_bank();

__device__ __forceinline__ float fast_exp2(float x) {
#if __has_builtin(__builtin_amdgcn_exp2f)
    return __builtin_amdgcn_exp2f(x);
#else
    return __expf(x * 0.6931471805599453f);
#endif
}

// ---------------------------------------------------------------------------
// Deterministic packed-f16 ops via single-instruction inline asm (int-typed
// operands = one VGPR each; single-inst wrappers keep scheduler freedom).
// Round-7 post-mortem: op_sel is not accepted on VOP1 f16 trans ops by the
// gfx950 assembler — hi-half handled via lshr/lshl + v_bfi_b32 instead.
// ---------------------------------------------------------------------------
__device__ __forceinline__ int pk_fma(int a, int b, int c) {
    int d;
    asm("v_pk_fma_f16 %0, %1, %2, %3" : "=v"(d) : "v"(a), "v"(b), "v"(c));
    return d;
}
__device__ __forceinline__ int pk_mul(int a, int b) {
    int d;
    asm("v_pk_mul_f16 %0, %1, %2" : "=v"(d) : "v"(a), "v"(b));
    return d;
}
__device__ __forceinline__ int pk_add(int a, int b) {
    int d;
    asm("v_pk_add_f16 %0, %1, %2" : "=v"(d) : "v"(a), "v"(b));
    return d;
}
__device__ __forceinline__ int sh_r16(int a) {
    int d;
    asm("v_lshrrev_b32 %0, 16, %1" : "=v"(d) : "v"(a));
    return d;
}
__device__ __forceinline__ int sh_l16(int a) {
    int d;
    asm("v_lshlrev_b32 %0, 16, %1" : "=v"(d) : "v"(a));
    return d;
}
// lower 16 bits valid; upper bits of dest are junk (never read downstream)
__device__ __forceinline__ int exp16(int z) {
    int r;
    asm("v_exp_f16 %0, %1" : "=v"(r) : "v"(z));
    return r;
}
__device__ __forceinline__ int rcp16(int z) {
    int r;
    asm("v_rcp_f16 %0, %1" : "=v"(r) : "v"(z));
    return r;
}
// D = (S0&S1) | (~S0&S2): mask 0xFFFF -> lo from S1, hi from S2
__device__ __forceinline__ int bfi16(int mask, int lo, int hi) {
    int d;
    asm("v_bfi_b32 %0, %1, %2, %3" : "=v"(d) : "v"(mask), "v"(lo), "v"(hi));
    return d;
}
// 2-wide f16 dot with f32 accumulate: one v_dot2_f32_f16.
__device__ __forceinline__ void dot2_acc(float& acc, int a, int b) {
    asm("v_dot2_f32_f16 %0, %1, %2, %0" : "+v"(acc) : "v"(a), "v"(b));
}

__device__ __forceinline__ int pk2i(float a, float b) {
    return __builtin_bit_cast(int, __builtin_amdgcn_cvt_pkrtz(a, b));
}

__device__ __forceinline__ float ldz(const float* __restrict__ xb, int tt) {
    if (tt < 0 || tt >= T_LEN) return 0.0f;
    return xb[tt * C_LEN];
}

// ---------------------------------------------------------------------------
// Per-thread worker: one channel c, 4 consecutive t starting at t0.
// CHECKED=true handles series edges (zero-pad conv, reflect-pad pooling).
//
// Conv/pool identical to the proven round-0 kernel. Conditioner MLP: hidden
// units in pairs, all-asm packed-f16 chain: 3 pk_fma pre + 3 pk poly +
// 10-inst sigmoid tail (2 trans exp + 2 trans rcp on split halves) + 5
// v_dot2_f32_f16 logit accumulates -> f32 logits. 21 insts per pair per
// position vs ~30 scalar. Softmax max-subtract dropped (|logit·log2e| << 127,
// proven safe rounds 1-4; exp2h saturation exact).
// wpk[p][0..8]: pair p = hidden units (2p,2p+1), f16-packed weights;
// [0..3] = W1 rows + b1, [4..8] = W2 cols 0..4 (x log2e). Wave-uniform LDS
// reads -> broadcast, no conflicts.
// ---------------------------------------------------------------------------
template <bool CHECKED>
__device__ __forceinline__ void work(const float* __restrict__ x,
                                     float* __restrict__ out,
                                     const int (*__restrict__ wpk)[12],
                                     const float* __restrict__ b2l,
                                     int b, int t0, int c) {
    const float* xb = x + (size_t)b * T_LEN * C_LEN + c;  // index by t*C_LEN

    // ---- pooling window values: x[t0-7 .. t0+11] (reflect at edges) ----
    float v[19];
#pragma unroll
    for (int i = 0; i < 19; ++i) {
        int tt = t0 - 7 + i;
        if (CHECKED) {
            tt = (tt < 0) ? -tt : tt;
            tt = (tt >= T_LEN) ? (2 * T_LEN - 2 - tt) : tt;
        }
        v[i] = xb[tt * C_LEN];
    }

    float mean[4], var[4], xc[4];
    {
        float s = 0.f, q = 0.f;
#pragma unroll
        for (int i = 0; i < 16; ++i) { s += v[i]; q = fmaf(v[i], v[i], q); }
#pragma unroll
        for (int m = 0; m < 4; ++m) {
            if (m > 0) {
                float nw = v[15 + m], od = v[m - 1];
                s = s + nw - od;
                q = fmaf(nw, nw, fmaf(od, -od, q));
            }
            mean[m] = s * 0.0625f;
            float m2 = q * 0.0625f;
            float vv = fmaf(-mean[m], mean[m], m2);
            var[m] = vv > 0.f ? vv : 0.f;
            xc[m]  = v[7 + m];   // x[t0+m] (always in range -> reflect is identity)
        }
    }

    // ---- duplicate-packed feats for the packed-pair MLP ----
    int meanP[4], varP[4], xcP[4];
#pragma unroll
    for (int m = 0; m < 4; ++m) {
        meanP[m] = pk2i(mean[m], mean[m]);
        varP[m]  = pk2i(var[m],  var[m]);
        xcP[m]   = pk2i(xc[m],   xc[m]);
    }

    // ---- 5 Gaussian convs, symmetric-pair register sliding windows ----
    float acc[5][4];
#pragma unroll
    for (int k = 0; k < 5; ++k)
#pragma unroll
        for (int m = 0; m < 4; ++m) acc[k][m] = BANK.g[k][0] * xc[m];

    float F[4], Bw[4];
    if (CHECKED) {
        F[1] = ldz(xb, t0 + 1); F[2] = ldz(xb, t0 + 2);
        F[3] = ldz(xb, t0 + 3); F[0] = ldz(xb, t0 + 4);
        Bw[3] = ldz(xb, t0 - 1); Bw[0] = ldz(xb, t0);
        Bw[1] = ldz(xb, t0 + 1); Bw[2] = ldz(xb, t0 + 2);
    } else {
        F[1] = v[8]; F[2] = v[9]; F[3] = v[10]; F[0] = v[11];
        Bw[3] = v[6]; Bw[0] = v[7]; Bw[1] = v[8]; Bw[2] = v[9];
    }

#pragma unroll
    for (int j = 1; j <= 56; ++j) {
        float sm[4];
#pragma unroll
        for (int m = 0; m < 4; ++m)
            sm[m] = F[(j + m) & 3] + Bw[(m - j) & 3];
#pragma unroll
        for (int k = 0; k < 5; ++k) {
            if (j <= RAD[k]) {
#pragma unroll
                for (int m = 0; m < 4; ++m)
                    acc[k][m] = fmaf(BANK.g[k][j], sm[m], acc[k][m]);
            }
        }
        if (j < 56) {
            if (CHECKED) {
                F[j & 3]        = ldz(xb, t0 + j + 4);
                Bw[(3 - j) & 3] = ldz(xb, t0 - j - 1);
            } else {
                F[j & 3]        = (j <= 7) ? v[j + 11] : xb[(t0 + j + 4) * C_LEN];
                Bw[(3 - j) & 3] = (j <= 6) ? v[6 - j]  : xb[(t0 - j - 1) * C_LEN];
            }
        }
    }

    // ---- conditioner MLP: 16 hidden-unit pairs, all-asm packed f16 ----
    float lg[5][4];
#pragma unroll
    for (int k = 0; k < 5; ++k) {
        float bk = b2l[k];
#pragma unroll
        for (int m = 0; m < 4; ++m) lg[k][m] = bk;
    }

    // gelu tanh-form constants (pre-scaled by log2e), f16-packed
    const float c1f = (float)(-2.0 * 0.7978845608028654 * 1.4426950408889634);
    const int C1P = pk2i(c1f, c1f);
    const int C2P = pk2i(c1f * 0.044715f, c1f * 0.044715f);
    const int ONE = 0x3C003C00;   // (1.0h, 1.0h)
    const int MSK = 0x0000FFFF;   // bfi lo-mask (VGPR; VOP3 forbids literals)

#pragma unroll 2
    for (int p = 0; p < 16; ++p) {
        const int4 wA = *(const int4*)&wpk[p][0];   // w1r0, w1r1, w1r2, b1
        const int4 wB = *(const int4*)&wpk[p][4];   // w2 cols 0..3 (x log2e)
        const int  w4 = wpk[p][8];                  // w2 col 4    (x log2e)
#pragma unroll
        for (int m = 0; m < 4; ++m) {
            int pre = pk_fma(wA.x, meanP[m], wA.w);
            pre = pk_fma(wA.y, varP[m], pre);
            pre = pk_fma(wA.z, xcP[m],  pre);
            // fast GELU: v*sigmoid(1.596(v+0.0447v^3)); zz = -log2e*1.596*(..)
            // pre=+big: zz->-big, exp2~0, rcp(1)=1, h=pre (correct)
            // pre=-big: zz->+big, exp2=inf, rcp(inf)=0, h=0  (correct)
            int v2 = pk_mul(pre, pre);
            int tt = pk_fma(v2, C2P, C1P);
            int zz = pk_mul(pre, tt);
            int zh  = sh_r16(zz);
            int elo = exp16(zz);              // lower half valid
            int ehi = exp16(zh);
            int dlo = pk_add(elo, ONE);       // junk uppers, lo lane correct
            int dhi = pk_add(ehi, ONE);
            int rlo = rcp16(dlo);
            int rhi = rcp16(dhi);
            int rr  = bfi16(MSK, rlo, sh_l16(rhi));
            int hh  = pk_mul(pre, rr);
            dot2_acc(lg[0][m], hh, wB.x);
            dot2_acc(lg[1][m], hh, wB.y);
            dot2_acc(lg[2][m], hh, wB.z);
            dot2_acc(lg[3][m], hh, wB.w);
            dot2_acc(lg[4][m], hh, w4);
        }
    }

    // ---- softmax over K=5 (logits x log2e, max-free: |l| << 127) + mix ----
#pragma unroll
    for (int m = 0; m < 4; ++m) {
        float e0 = fast_exp2(lg[0][m]);
        float e1 = fast_exp2(lg[1][m]);
        float e2 = fast_exp2(lg[2][m]);
        float e3 = fast_exp2(lg[3][m]);
        float e4 = fast_exp2(lg[4][m]);
        float den = ((e0 + e1) + (e2 + e3)) + e4;
        float num = e0 * acc[0][m];
        num = fmaf(e1, acc[1][m], num);
        num = fmaf(e2, acc[2][m], num);
        num = fmaf(e3, acc[3][m], num);
        num = fmaf(e4, acc[4][m], num);
        out[((size_t)b * T_LEN + t0 + m) * C_LEN + c] = num * __builtin_amdgcn_rcpf(den);
    }
}

// ---------------------------------------------------------------------------
// Single fused kernel: boundary chunks (28/1024 per b) take the CHECKED path,
// block-uniform branch. Weight staging: 16 pairs x 9 packed dwords (768B LDS),
// built by threads 0..15; all MLP-phase reads are wave-uniform broadcasts.
// __launch_bounds__(256) plain — round-2 post-mortem: (256,4) halves the
// unified register file and spills the conv phase to scratch (3x slowdown).
// ---------------------------------------------------------------------------
__global__ __launch_bounds__(256) void agt_fused(
    const float* __restrict__ x, const float* __restrict__ W1,
    const float* __restrict__ b1, const float* __restrict__ W2,
    const float* __restrict__ b2, float* __restrict__ out) {
    __shared__ __align__(16) int wpk[16][12];
    __shared__ float b2l[5];
    {
        int tid = threadIdx.x;
        if (tid < 16) {
            const int h0 = 2 * tid, h1 = 2 * tid + 1;
            wpk[tid][0] = pk2i(W1[h0],      W1[h1]);
            wpk[tid][1] = pk2i(W1[32 + h0], W1[32 + h1]);
            wpk[tid][2] = pk2i(W1[64 + h0], W1[64 + h1]);
            wpk[tid][3] = pk2i(b1[h0],      b1[h1]);
#pragma unroll
            for (int k = 0; k < 5; ++k)
                wpk[tid][4 + k] = pk2i(W2[h0 * 5 + k] * LOG2E,
                                       W2[h1 * 5 + k] * LOG2E);
            wpk[tid][9] = wpk[tid][10] = wpk[tid][11] = 0;
        }
        if (tid < 5) b2l[tid] = b2[tid] * LOG2E;
        __syncthreads();
    }
    int b     = blockIdx.x >> 10;        // 1024 chunks per batch
    int chunk = blockIdx.x & 1023;
    int t0    = chunk * 4;
    if (chunk >= 14 && chunk < 1010)
        work<false>(x, out, wpk, b2l, b, t0, threadIdx.x);
    else
        work<true>(x, out, wpk, b2l, b, t0, threadIdx.x);
}

extern "C" void kernel_launch(void* const* d_in, const int* in_sizes, int n_in,
                              void* d_out, int out_size, void* d_ws, size_t ws_size,
                              hipStream_t stream) {
    const float* x  = (const float*)d_in[0];
    const float* W1 = (const float*)d_in[1];
    const float* b1 = (const float*)d_in[2];
    const float* W2 = (const float*)d_in[3];
    const float* b2 = (const float*)d_in[4];
    float* out = (float*)d_out;

    (void)in_sizes; (void)n_in; (void)d_ws; (void)ws_size; (void)out_size;

    agt_fused<<<dim3(B_LEN * 1024), dim3(256), 0, stream>>>(x, W1, b1, W2, b2, out);
}